// Round 5
// baseline (883.671 us; speedup 1.0000x reference)
//
#include <hip/hip_runtime.h>

#define POP   128
#define BATCH 256
#define DIN   1024
#define DOUT  1024

#define BM 128
#define BN 128
#define BK 32
#define NKT (DIN / BK)

typedef __attribute__((ext_vector_type(8))) short  short8v;
typedef __attribute__((ext_vector_type(4))) float  float4v;

typedef __attribute__((address_space(1))) const unsigned guint;
typedef __attribute__((address_space(3))) unsigned       luint;

// fp32 -> bf16 round-to-nearest-even (inputs are finite Gaussians; no NaN path)
static __device__ __forceinline__ short f2bf(float f) {
    unsigned u = __builtin_bit_cast(unsigned, f);
    u += 0x7fffu + ((u >> 16) & 1u);
    return (short)(u >> 16);
}

// async global->LDS DMA, 16B per lane. LDS dest is wave-uniform base + lane*16
// (m104); global src is per-lane. Size must be a literal (16).
static __device__ __forceinline__ void gload_lds16(const float* g, float* l) {
    __builtin_amdgcn_global_load_lds((guint*)g, (luint*)l, 16, 0, 0);
}

__global__ __launch_bounds__(256, 4)
void pop_linear_kernel(const float* __restrict__ x,
                       const float* __restrict__ w,
                       const float* __restrict__ bias,
                       float* __restrict__ out) {
    // fp32 tiles, single-buffered: 2 * 128*32*4B = 32 KB -> 4 blocks/CU.
    // Layout: linear row-major [128][32] BUT each row's bytes are stored
    // XOR-swizzled: phys_inrow_byte = logical_inrow_byte ^ ((row&7)<<4).
    // DMA writes linearly; the global SOURCE address carries the inverse
    // permutation (same involution), reads apply the XOR again (rule #21).
    __shared__ float As[BM * BK];
    __shared__ float Bs[BN * BK];

    const int bid = blockIdx.x;
    // p slow, m_tile middle (stride 8 -> same XCD pair shares W tile), n_tile fast
    const int p      = bid >> 4;
    const int m_tile = (bid >> 3) & 1;
    const int n_tile = bid & 7;

    const int tid    = threadIdx.x;
    const int lane   = tid & 63;
    const int wave   = tid >> 6;   // 0..3
    const int wm     = wave >> 1;  // 0..1  (row half for MFMA)
    const int wn     = wave & 1;   // 0..1  (col half for MFMA)
    const int lane15 = lane & 15;
    const int quad   = lane >> 4;  // 0..3

    const int m_base = m_tile * BM;
    const int n_base = n_tile * BN;

    // ---- DMA staging roles: waves 0,1 -> A halves; waves 2,3 -> B halves ----
    // Each gload_lds16 instr g covers 8 rows x 32 fp32 (1 KB): lane l writes
    // LDS byte (half*64 + g*8)*128 + l*16  ->  row = base + g*8 + (l>>3),
    // phys inrow byte = (l&7)*16, so the logical col this lane must FETCH is
    // ((l&7)*16) ^ ((l>>3)<<4)  (row&7 == l>>3 since bases are multiples of 8).
    const bool isA  = wave < 2;
    const int  half = wave & 1;
    const int  lrow = lane >> 3;                     // 0..7
    const int  lcol = 4 * ((lane & 7) ^ lrow);       // swizzled logical col (floats)

    const float* gbase;
    size_t grstride;  // floats between consecutive tile rows
    float* lbase;
    if (isA) {
        gbase    = x + (size_t)(m_base + half * 64 + lrow) * (POP * DIN) + (size_t)p * DIN + lcol;
        grstride = (size_t)POP * DIN;
        lbase    = As + (half * 64) * BK;
    } else {
        gbase    = w + (size_t)p * ((size_t)DOUT * DIN) + (size_t)(n_base + half * 64 + lrow) * DIN + lcol;
        grstride = DIN;
        lbase    = Bs + (half * 64) * BK;
    }

    float4v acc[4][4];
    #pragma unroll
    for (int i = 0; i < 4; ++i)
        #pragma unroll
        for (int j = 0; j < 4; ++j)
            acc[i][j] = (float4v){0.f, 0.f, 0.f, 0.f};

    // fragment-read swizzle constants (same involution as the source side)
    const char* Ac = (const char*)As;
    const char* Bc = (const char*)Bs;
    const int xr = (lane15 & 7) << 4;          // row-dependent XOR (bytes)
    const int c0 = (quad * 32) ^ xr;           // phys byte of logical k-chunk lo
    const int c1 = (quad * 32 + 16) ^ xr;      // phys byte of logical k-chunk hi

    #pragma unroll 1
    for (int kt = 0; kt < NKT; ++kt) {
        // ---- issue 8 DMA loads (1 KB each) for this K-tile ----
        #pragma unroll
        for (int g = 0; g < 8; ++g)
            gload_lds16(gbase + (size_t)(g * 8) * grstride + kt * BK, lbase + g * 256);

        __syncthreads();   // drains vmcnt(0): DMA landed; all waves' tiles ready

        // ---- fragments: A[m = lane&15][k = quad*8 + e], B mirrors (n = lane&15)
        short8v bfr[4];
        #pragma unroll
        for (int j = 0; j < 4; ++j) {
            const int row = wn * 64 + j * 16 + lane15;
            float4v lo = *(const float4v*)(Bc + row * 128 + c0);
            float4v hi = *(const float4v*)(Bc + row * 128 + c1);
            short8v b;
            #pragma unroll
            for (int e = 0; e < 4; ++e) { b[e] = f2bf(lo[e]); b[4 + e] = f2bf(hi[e]); }
            bfr[j] = b;
        }
        #pragma unroll
        for (int i = 0; i < 4; ++i) {
            const int row = wm * 64 + i * 16 + lane15;
            float4v lo = *(const float4v*)(Ac + row * 128 + c0);
            float4v hi = *(const float4v*)(Ac + row * 128 + c1);
            short8v a;
            #pragma unroll
            for (int e = 0; e < 4; ++e) { a[e] = f2bf(lo[e]); a[4 + e] = f2bf(hi[e]); }
            #pragma unroll
            for (int j = 0; j < 4; ++j)
                acc[i][j] = __builtin_amdgcn_mfma_f32_16x16x32_bf16(a, bfr[j], acc[i][j], 0, 0, 0);
        }

        __syncthreads();   // all frag reads done before next tile's DMA overwrites
    }

    // epilogue: C/D layout m = quad*4 + reg, n = lane&15
    const float* bp = bias + (size_t)p * DOUT;
    float bj[4];
    #pragma unroll
    for (int j = 0; j < 4; ++j)
        bj[j] = bp[n_base + wn * 64 + j * 16 + lane15];

    #pragma unroll
    for (int i = 0; i < 4; ++i) {
        #pragma unroll
        for (int r = 0; r < 4; ++r) {
            const int m = m_base + wm * 64 + i * 16 + quad * 4 + r;
            float* orow = out + (size_t)m * (POP * DOUT) + (size_t)p * DOUT;
            #pragma unroll
            for (int j = 0; j < 4; ++j) {
                const int n = n_base + wn * 64 + j * 16 + lane15;
                orow[n] = acc[i][j][r] + bj[j];
            }
        }
    }
}

extern "C" void kernel_launch(void* const* d_in, const int* in_sizes, int n_in,
                              void* d_out, int out_size, void* d_ws, size_t ws_size,
                              hipStream_t stream) {
    const float* x    = (const float*)d_in[0];
    const float* w    = (const float*)d_in[1];
    const float* bias = (const float*)d_in[2];
    float* out        = (float*)d_out;

    const int grid = POP * (BATCH / BM) * (DOUT / BN);  // 128 * 2 * 8 = 2048
    pop_linear_kernel<<<grid, 256, 0, stream>>>(x, w, bias, out);
}

// Round 6
// 871.992 us; speedup vs baseline: 1.0134x; 1.0134x over previous
//
#include <hip/hip_runtime.h>

#define POP   128
#define BATCH 256
#define DIN   1024
#define DOUT  1024

#define BM 128
#define BN 128
#define BK 128            // 512 B contiguous per row per stage (was 128 B) -> DRAM burst efficiency
#define NKT (DIN / BK)    // 8

typedef __attribute__((ext_vector_type(8))) short  short8v;
typedef __attribute__((ext_vector_type(4))) short  short4v;
typedef __attribute__((ext_vector_type(4))) float  float4v;

// fp32 -> bf16 round-to-nearest-even (inputs are finite Gaussians; no NaN path)
static __device__ __forceinline__ short f2bf(float f) {
    unsigned u = __builtin_bit_cast(unsigned, f);
    u += 0x7fffu + ((u >> 16) & 1u);
    return (short)(u >> 16);
}

// LDS-only barrier (round-3 verified): drains ds ops but NOT vmcnt, so staged
// global loads stay in flight across it. Both barriers in this kernel guard
// LDS hazards only (global loads land in private VGPRs).
static __device__ __forceinline__ void lds_barrier() {
    asm volatile("s_waitcnt lgkmcnt(0)\n\ts_barrier" ::: "memory");
}

__global__ __launch_bounds__(256, 2)
void pop_linear_kernel(const float* __restrict__ x,
                       const float* __restrict__ w,
                       const float* __restrict__ bias,
                       float* __restrict__ out) {
    // bf16 tiles [128 rows][128 k], row stride 256 B, single-buffered: 64 KB -> 2 blocks/CU.
    // In-row bytes XOR-swizzled: phys = logical ^ ((row&7)<<4)  (T2; applied on BOTH
    // ds_write and ds_read sides -- legal because staging is reg-staged, not DMA).
    __shared__ short As[BM * BK];
    __shared__ short Bs[BN * BK];

    const int bid = blockIdx.x;
    // p slow, m_tile middle (stride 8 -> w-panel sharers land on same XCD), n_tile fast
    const int p      = bid >> 4;
    const int m_tile = (bid >> 3) & 1;
    const int n_tile = bid & 7;

    const int tid    = threadIdx.x;
    const int lane   = tid & 63;
    const int wave   = tid >> 6;   // 0..3
    const int wm     = wave >> 1;  // 0..1  (row half)
    const int wn     = wave & 1;   // 0..1  (col half)
    const int lane15 = lane & 15;
    const int quad   = lane >> 4;  // 0..3

    const int m_base = m_tile * BM;
    const int n_base = n_tile * BN;

    // staging geometry: pass ps covers rows ps*8 + srow8; 32 lanes x float4 = 512 B
    // contiguous per row. 16 passes cover 128 rows x 128 k (one tile); A and B each.
    const int srow8 = tid >> 5;          // 0..7
    const int scolf = (tid & 31) * 4;    // 0..124 (floats)

    const float* Ag = x + (size_t)(m_base + srow8) * (POP * DIN) + (size_t)p * DIN + scolf;
    const float* Bg = w + (size_t)p * ((size_t)DOUT * DIN) + (size_t)(n_base + srow8) * DIN + scolf;

    // LDS write byte offset within row (constant across passes: (ps*8+srow8)&7 == srow8)
    const int swz = (scolf * 2) ^ (srow8 << 4);

    float4v acc[4][4];
    #pragma unroll
    for (int i = 0; i < 4; ++i)
        #pragma unroll
        for (int j = 0; j < 4; ++j)
            acc[i][j] = (float4v){0.f, 0.f, 0.f, 0.f};

    // stage registers: 32 float4 in flight (~128 VGPR) -- single set; reused for
    // the next issue only AFTER cvt_write consumed them (WAR on regs orders it).
    float4v avr[16], bvr[16];

    // fragment-read swizzle: row&7 == lane15&7 for all fragment rows (bases %8==0)
    const int frx = (lane15 & 7) << 4;
    const char* Ac = (const char*)As;
    const char* Bc = (const char*)Bs;

    // ---- prologue: issue stage 0 ----
    #pragma unroll
    for (int ps = 0; ps < 16; ++ps) {
        avr[ps] = *(const float4v*)(Ag + (size_t)(ps * 8) * (POP * DIN));
        bvr[ps] = *(const float4v*)(Bg + (size_t)(ps * 8) * DIN);
    }

    #pragma unroll 1
    for (int kt = 0; kt < NKT; ++kt) {
        lds_barrier();   // all waves' LDS reads of previous stage done

        // convert + publish (compiler inserts exact vmcnt waits for avr/bvr uses)
        #pragma unroll
        for (int ps = 0; ps < 16; ++ps) {
            short4v a4, b4;
            #pragma unroll
            for (int e = 0; e < 4; ++e) {
                a4[e] = f2bf(avr[ps][e]);
                b4[e] = f2bf(bvr[ps][e]);
            }
            *(short4v*)((char*)As + (ps * 8 + srow8) * 256 + swz) = a4;
            *(short4v*)((char*)Bs + (ps * 8 + srow8) * 256 + swz) = b4;
        }

        lds_barrier();   // writes visible to all waves

        // issue next stage -- these loads fly across the whole compute phase
        if (kt + 1 < NKT) {
            const size_t k0 = (size_t)(kt + 1) * BK;
            #pragma unroll
            for (int ps = 0; ps < 16; ++ps) {
                avr[ps] = *(const float4v*)(Ag + (size_t)(ps * 8) * (POP * DIN) + k0);
                bvr[ps] = *(const float4v*)(Bg + (size_t)(ps * 8) * DIN + k0);
            }
        }

        // compute: 4 k-chunks of 32, 16 MFMA each; fragments A[m=lane15][k=quad*8+e]
        #pragma unroll
        for (int kk = 0; kk < 4; ++kk) {
            const int cb = (kk * 64 + quad * 16) ^ frx;   // phys byte of this k-chunk
            short8v bfr[4];
            #pragma unroll
            for (int j = 0; j < 4; ++j)
                bfr[j] = *(const short8v*)(Bc + (wn * 64 + j * 16 + lane15) * 256 + cb);
            #pragma unroll
            for (int i = 0; i < 4; ++i) {
                short8v afr = *(const short8v*)(Ac + (wm * 64 + i * 16 + lane15) * 256 + cb);
                #pragma unroll
                for (int j = 0; j < 4; ++j)
                    acc[i][j] = __builtin_amdgcn_mfma_f32_16x16x32_bf16(afr, bfr[j], acc[i][j], 0, 0, 0);
            }
        }
    }

    // epilogue: C/D layout m = quad*4 + reg, n = lane&15 (unchanged, HW-verified)
    const float* bp = bias + (size_t)p * DOUT;
    float bj[4];
    #pragma unroll
    for (int j = 0; j < 4; ++j)
        bj[j] = bp[n_base + wn * 64 + j * 16 + lane15];

    #pragma unroll
    for (int i = 0; i < 4; ++i) {
        #pragma unroll
        for (int r = 0; r < 4; ++r) {
            const int m = m_base + wm * 64 + i * 16 + quad * 4 + r;
            float* orow = out + (size_t)m * (POP * DOUT) + (size_t)p * DOUT;
            #pragma unroll
            for (int j = 0; j < 4; ++j) {
                const int n = n_base + wn * 64 + j * 16 + lane15;
                orow[n] = acc[i][j][r] + bj[j];
            }
        }
    }
}

extern "C" void kernel_launch(void* const* d_in, const int* in_sizes, int n_in,
                              void* d_out, int out_size, void* d_ws, size_t ws_size,
                              hipStream_t stream) {
    const float* x    = (const float*)d_in[0];
    const float* w    = (const float*)d_in[1];
    const float* bias = (const float*)d_in[2];
    float* out        = (float*)d_out;

    const int grid = POP * (BATCH / BM) * (DOUT / BN);  // 128 * 2 * 8 = 2048
    pop_linear_kernel<<<grid, 256, 0, stream>>>(x, w, bias, out);
}

// Round 7
// 853.012 us; speedup vs baseline: 1.0359x; 1.0223x over previous
//
#include <hip/hip_runtime.h>

#define POP   128
#define BATCH 256
#define DIN   1024
#define DOUT  1024

#define BM 256            // full batch: w panel loaded ONCE (was 2x)
#define BN 256            // x panel loaded 4x (was 8x) -> issued loads 2.14 GB -> 1.07 GB
#define BK 64
#define NKT (DIN / BK)    // 16

typedef __attribute__((ext_vector_type(8))) short  short8v;
typedef __attribute__((ext_vector_type(4))) short  short4v;
typedef __attribute__((ext_vector_type(4))) float  float4v;

// fp32 -> bf16 round-to-nearest-even (inputs are finite Gaussians; no NaN path)
static __device__ __forceinline__ short f2bf(float f) {
    unsigned u = __builtin_bit_cast(unsigned, f);
    u += 0x7fffu + ((u >> 16) & 1u);
    return (short)(u >> 16);
}

// LDS-only barrier (HW-verified rounds 3/6): drains ds ops but NOT vmcnt, so
// staged global loads stay in flight across it. Both barriers here guard LDS
// hazards only (global loads land in private VGPRs; exact vmcnt waits for
// their register uses are compiler-inserted at the convert).
static __device__ __forceinline__ void lds_barrier() {
    asm volatile("s_waitcnt lgkmcnt(0)\n\ts_barrier" ::: "memory");
}

__global__ __launch_bounds__(512, 2)
void pop_linear_kernel(const float* __restrict__ x,
                       const float* __restrict__ w,
                       const float* __restrict__ bias,
                       float* __restrict__ out) {
    // bf16 tiles [256 rows][64 k], row stride 128 B, single-buffered: 64 KB total.
    // In-row bytes XOR-swizzled: phys = logical ^ ((row&7)<<4), applied on BOTH
    // ds_write and ds_read sides (T2; legal because staging is reg-staged).
    __shared__ short As[BM * BK];   // 32 KB
    __shared__ short Bs[BN * BK];   // 32 KB

    // grid 512 = 128 pops x 4 n_tiles. bid%8 == p%8 -> the 4 n-sharers of a pop
    // (same x panel) land on one XCD (round-robin heuristic): x reads hit L2.
    const int bid    = blockIdx.x;
    const int k      = bid >> 3;
    const int n_tile = k & 3;
    const int p      = ((k >> 2) << 3) | (bid & 7);

    const int tid    = threadIdx.x;        // 0..511
    const int lane   = tid & 63;
    const int wave   = tid >> 6;           // 0..7 = 2(m) x 4(n)
    const int wm     = wave >> 2;          // 0..1  (row half: 128 rows each)
    const int wn     = wave & 3;           // 0..3  (col quarter: 64 cols each)
    const int lane15 = lane & 15;
    const int quad   = lane >> 4;          // 0..3

    const int n_base = n_tile * BN;

    // staging: thread -> row srow + 32*ps (8 passes), 256 B contiguous per row
    // covered by 16 lanes x float4
    const int srow  = tid >> 4;            // 0..31
    const int scolf = (tid & 15) * 4;      // 0..60 (floats)

    const float* Ag = x + (size_t)srow * (POP * DIN) + (size_t)p * DIN + scolf;
    const float* Bg = w + (size_t)p * ((size_t)DOUT * DIN) + (size_t)(n_base + srow) * DIN + scolf;

    // write-side swizzle: (ps*32+srow)&7 == srow&7, so constant across passes
    const int swz = (scolf * 2) ^ ((srow & 7) << 4);

    float4v acc[8][4];
    #pragma unroll
    for (int i = 0; i < 8; ++i)
        #pragma unroll
        for (int j = 0; j < 4; ++j)
            acc[i][j] = (float4v){0.f, 0.f, 0.f, 0.f};

    // stage registers: 16 float4 in flight (64 VGPR)
    float4v avr[8], bvr[8];

    // read-side swizzle: fragment rows have row&7 == lane15&7 (bases %8 == 0)
    const int frx = (lane15 & 7) << 4;
    const char* Ac = (const char*)As;
    const char* Bc = (const char*)Bs;

    // ---- prologue: issue stage 0 ----
    #pragma unroll
    for (int ps = 0; ps < 8; ++ps) {
        avr[ps] = *(const float4v*)(Ag + (size_t)(ps * 32) * (POP * DIN));
        bvr[ps] = *(const float4v*)(Bg + (size_t)(ps * 32) * DIN);
    }

    #pragma unroll 1
    for (int kt = 0; kt < NKT; ++kt) {
        lds_barrier();   // all waves' LDS reads of previous tile done

        // convert + publish (compiler inserts exact vmcnt waits for avr/bvr)
        #pragma unroll
        for (int ps = 0; ps < 8; ++ps) {
            short4v a4, b4;
            #pragma unroll
            for (int e = 0; e < 4; ++e) {
                a4[e] = f2bf(avr[ps][e]);
                b4[e] = f2bf(bvr[ps][e]);
            }
            *(short4v*)((char*)As + (ps * 32 + srow) * 128 + swz) = a4;
            *(short4v*)((char*)Bs + (ps * 32 + srow) * 128 + swz) = b4;
        }

        lds_barrier();   // writes visible to all waves

        // issue next stage -- flies across compute AND the next convert's drain
        if (kt + 1 < NKT) {
            const size_t k0 = (size_t)(kt + 1) * BK;
            #pragma unroll
            for (int ps = 0; ps < 8; ++ps) {
                avr[ps] = *(const float4v*)(Ag + (size_t)(ps * 32) * (POP * DIN) + k0);
                bvr[ps] = *(const float4v*)(Bg + (size_t)(ps * 32) * DIN + k0);
            }
        }

        // compute: 2 k-chunks of 32; per wave 8x4 fragments, 64 MFMA per step
        #pragma unroll
        for (int kk = 0; kk < 2; ++kk) {
            const int cb = (kk * 64 + quad * 16) ^ frx;   // phys in-row byte
            short8v bfr[4];
            #pragma unroll
            for (int j = 0; j < 4; ++j)
                bfr[j] = *(const short8v*)(Bc + (wn * 64 + j * 16 + lane15) * 128 + cb);
            #pragma unroll
            for (int i = 0; i < 8; ++i) {
                short8v afr = *(const short8v*)(Ac + (wm * 128 + i * 16 + lane15) * 128 + cb);
                #pragma unroll
                for (int j = 0; j < 4; ++j)
                    acc[i][j] = __builtin_amdgcn_mfma_f32_16x16x32_bf16(afr, bfr[j], acc[i][j], 0, 0, 0);
            }
        }
    }

    // epilogue: C/D layout m = quad*4 + reg, n = lane&15 (HW-verified mapping)
    const float* bp = bias + (size_t)p * DOUT;
    float bj[4];
    #pragma unroll
    for (int j = 0; j < 4; ++j)
        bj[j] = bp[n_base + wn * 64 + j * 16 + lane15];

    #pragma unroll
    for (int i = 0; i < 8; ++i) {
        #pragma unroll
        for (int r = 0; r < 4; ++r) {
            const int m = wm * 128 + i * 16 + quad * 4 + r;
            float* orow = out + (size_t)m * (POP * DOUT) + (size_t)p * DOUT;
            #pragma unroll
            for (int j = 0; j < 4; ++j) {
                const int n = n_base + wn * 64 + j * 16 + lane15;
                orow[n] = acc[i][j][r] + bj[j];
            }
        }
    }
}

extern "C" void kernel_launch(void* const* d_in, const int* in_sizes, int n_in,
                              void* d_out, int out_size, void* d_ws, size_t ws_size,
                              hipStream_t stream) {
    const float* x    = (const float*)d_in[0];
    const float* w    = (const float*)d_in[1];
    const float* bias = (const float*)d_in[2];
    float* out        = (float*)d_out;

    const int grid = POP * (DOUT / BN);  // 128 * 4 = 512
    pop_linear_kernel<<<grid, 512, 0, stream>>>(x, w, bias, out);
}